// Round 15
// baseline (193.406 us; speedup 1.0000x reference)
//
#include <hip/hip_runtime.h>

// CRF log-partition forward, MI355X. 64 blocks (1 per sequence) x 256 threads
// (4 waves, pinned 1 wave/EU). R14 structure (f16 state + v_dot2_f32_f16 +
// quad-only DPP combine + lgkmcnt-only barrier + distance-4 prefetch) with
// chain micro-surgery:
//  - compile-time ping-pong: STEP_BODY expanded with literal buffer indices
//    (4 steps per loop iter, A->B->A->B) -- no 'cur' flip, LDS addresses are
//    base-register + offset immediates
//  - 8 fdot2 accumulator chains of depth 4 (was 4x8): shorter dep tail
//  - hoisted read/write pointers
// Numerics identical to R14 (absmax 4.0 vs threshold 54):
//   q' = exp2(e*log2e - eS) * (q . E_col),  eS = f16 exponent of old q0
//   o += eS (exact);  out = ln2 * (o + log2 sum_j q_j exp(end_j))

#define LOG2E 1.4426950408889634f
#define LN2   0.6931471805599453f

// LDS-only workgroup barrier: no vmcnt drain (cross-wave data is LDS only).
#define LDS_BARRIER() asm volatile("s_waitcnt lgkmcnt(0)\n\ts_barrier" ::: "memory")

typedef float    f2 __attribute__((ext_vector_type(2)));
typedef _Float16 h2 __attribute__((ext_vector_type(2)));

#define PKRTZ(a, b) __builtin_bit_cast(h2, __builtin_amdgcn_cvt_pkrtz((a), (b)))

template <int CTRL>
__device__ __forceinline__ float dpp_f(float x) {
    return __int_as_float(
        __builtin_amdgcn_mov_dpp(__float_as_int(x), CTRL, 0xF, 0xF, false));
}
// quad_perm codes: xor1 = 0xB1, xor2 = 0x4E

__global__ __launch_bounds__(256)
__attribute__((amdgpu_waves_per_eu(1, 1)))
void crf_forward(
    const float* __restrict__ emissions,   // [64, 512, 128]
    const float* __restrict__ transitions, // [128, 128]
    const float* __restrict__ start_t,     // [128]
    const float* __restrict__ end_t,       // [128]
    const int*   __restrict__ lengths,     // [64]
    float* __restrict__ out)               // [64]
{
    constexpr int N = 128;
    constexpr int L = 512;
    const int b   = blockIdx.x;
    const int tid = threadIdx.x;
    const int g   = tid >> 2;   // tag pair {2g, 2g+1}, g in [0,64)
    const int k   = tid & 3;    // i-chunk: tags [32k,32k+32) = pair-dwords [16k,16k+16)

    // f16-pair dwords; chunk k at padded base 20k (16B-aligned, disjoint banks)
    __shared__ alignas(16) float pbuf[2][80];
    __shared__ float wsum[4];

    // ---- one-time: E tile as 32 NAMED h2 registers (32 VGPRs).
    h2 EA_0,  EA_1,  EA_2,  EA_3,  EA_4,  EA_5,  EA_6,  EA_7;
    h2 EA_8,  EA_9,  EA_10, EA_11, EA_12, EA_13, EA_14, EA_15;
    h2 EB_0,  EB_1,  EB_2,  EB_3,  EB_4,  EB_5,  EB_6,  EB_7;
    h2 EB_8,  EB_9,  EB_10, EB_11, EB_12, EB_13, EB_14, EB_15;
    {
        const float* tb = transitions + (size_t)(32 * k) * N + 2 * g;
#define INIT_M(m)                                                              \
        {                                                                      \
            f2 r0 = *reinterpret_cast<const f2*>(tb + (size_t)(2 * (m)) * N);  \
            f2 r1 = *reinterpret_cast<const f2*>(tb + (size_t)(2 * (m) + 1) * N); \
            EA_##m = PKRTZ(__builtin_amdgcn_exp2f(r0.x * LOG2E),               \
                           __builtin_amdgcn_exp2f(r1.x * LOG2E));              \
            EB_##m = PKRTZ(__builtin_amdgcn_exp2f(r0.y * LOG2E),               \
                           __builtin_amdgcn_exp2f(r1.y * LOG2E));              \
        }
        INIT_M(0)  INIT_M(1)  INIT_M(2)  INIT_M(3)
        INIT_M(4)  INIT_M(5)  INIT_M(6)  INIT_M(7)
        INIT_M(8)  INIT_M(9)  INIT_M(10) INIT_M(11)
        INIT_M(12) INIT_M(13) INIT_M(14) INIT_M(15)
#undef INIT_M
    }

    const int len = lengths[b];
    const float* eb = emissions + (size_t)b * L * N;

    // hoisted LDS pointers (compile-time buffer bases -> offset immediates)
    const float4* const pv0 = reinterpret_cast<const float4*>(&pbuf[0][k * 20]);
    const float4* const pv1 = reinterpret_cast<const float4*>(&pbuf[1][k * 20]);
    float* const wr0 = &pbuf[0][(g >> 4) * 20 + (g & 15)];
    float* const wr1 = &pbuf[1][(g >> 4) * 20 + (g & 15)];

    // ---- init: raw q = exp(start + e0) for the lane's pair; k==0 writes buf0
    int o = 0;
    float qA, qB;
    {
        f2 st = *reinterpret_cast<const f2*>(start_t + 2 * g);
        f2 e0 = *reinterpret_cast<const f2*>(eb + 2 * g);
        qA = __builtin_amdgcn_exp2f((st.x + e0.x) * LOG2E);
        qB = __builtin_amdgcn_exp2f((st.y + e0.y) * LOG2E);
        if (k == 0) *wr0 = __builtin_bit_cast(float, PKRTZ(qA, qB));
    }
    LDS_BARRIER();

    auto clampt = [&](int tt) { return tt < len ? tt : len - 1; };
    auto ldE = [&](int tt) {
        return *reinterpret_cast<const f2*>(eb + (size_t)tt * N + 2 * g);
    };

    // one step: read buf SRC, write buf DST (literal indices)
#define STEP_BODY(PV, Q0W, WR, ecur)                                           \
    {                                                                          \
        float q0w = (Q0W);                                                     \
        float4 Q0 = (PV)[0], Q1 = (PV)[1], Q2 = (PV)[2], Q3 = (PV)[3];         \
        unsigned u0 = __float_as_uint(q0w);                                    \
        int eS = (int)((u0 >> 10) & 0x1Fu) - 15;                               \
        o += eS;                                                               \
        float feS = (float)eS;                                                 \
        float esA = __builtin_amdgcn_exp2f(ecur.x * LOG2E - feS);              \
        float esB = __builtin_amdgcn_exp2f(ecur.y * LOG2E - feS);              \
        float aA0 = 0.f, aA1 = 0.f, aA2 = 0.f, aA3 = 0.f;                      \
        float aB0 = 0.f, aB1 = 0.f, aB2 = 0.f, aB3 = 0.f;                      \
        DD(0,  Q0.x, 0) DD(1,  Q0.y, 1) DD(2,  Q0.z, 2) DD(3,  Q0.w, 3)        \
        DD(4,  Q1.x, 0) DD(5,  Q1.y, 1) DD(6,  Q1.z, 2) DD(7,  Q1.w, 3)        \
        DD(8,  Q2.x, 0) DD(9,  Q2.y, 1) DD(10, Q2.z, 2) DD(11, Q2.w, 3)        \
        DD(12, Q3.x, 0) DD(13, Q3.y, 1) DD(14, Q3.z, 2) DD(15, Q3.w, 3)        \
        float dA = (aA0 + aA1) + (aA2 + aA3);                                  \
        float dB = (aB0 + aB1) + (aB2 + aB3);                                  \
        dA += dpp_f<0xB1>(dA); dB += dpp_f<0xB1>(dB);                          \
        dA += dpp_f<0x4E>(dA); dB += dpp_f<0x4E>(dB);                          \
        qA = esA * dA;                                                         \
        qB = esB * dB;                                                         \
        if (k == 0) *(WR) = __builtin_bit_cast(float, PKRTZ(qA, qB));          \
        LDS_BARRIER();                                                         \
    }
#define DD(m, Qc, ch)                                                          \
        {                                                                      \
            h2 pm = __builtin_bit_cast(h2, Qc);                                \
            aA##ch = __builtin_amdgcn_fdot2(pm, EA_##m, aA##ch, false);        \
            aB##ch = __builtin_amdgcn_fdot2(pm, EB_##m, aB##ch, false);        \
        }

#define STEP_A(ecur) STEP_BODY(pv0, pbuf[0][0], wr1, ecur)   // buf0 -> buf1
#define STEP_B(ecur) STEP_BODY(pv1, pbuf[1][0], wr0, ecur)   // buf1 -> buf0

    // ---- main loop: distance-4 emission prefetch, 4 steps per iteration
    f2 ra = ldE(clampt(1));
    f2 rb = ldE(clampt(2));
    f2 rc = ldE(clampt(3));
    f2 rd = ldE(clampt(4));

    int t = 1;
    while (t < len) {
        STEP_A(ra); ra = ldE(clampt(t + 4)); ++t; if (t >= len) break;
        STEP_B(rb); rb = ldE(clampt(t + 4)); ++t; if (t >= len) break;
        STEP_A(rc); rc = ldE(clampt(t + 4)); ++t; if (t >= len) break;
        STEP_B(rd); rd = ldE(clampt(t + 4)); ++t;
    }
#undef STEP_A
#undef STEP_B
#undef DD
#undef STEP_BODY

    // ---- finalize: lane holds its pair's q in registers (x4 redundant)
    {
        f2 ef = *reinterpret_cast<const f2*>(end_t + 2 * g);
        float vend = qA * __builtin_amdgcn_exp2f(ef.x * LOG2E)
                   + qB * __builtin_amdgcn_exp2f(ef.y * LOG2E);
        vend *= 0.25f;
        #pragma unroll
        for (int m = 1; m < 64; m <<= 1) vend += __shfl_xor(vend, m);
        if ((tid & 63) == 0) wsum[tid >> 6] = vend;
    }
    LDS_BARRIER();
    if (tid == 0)
        out[b] = LN2 * ((float)o + __builtin_amdgcn_logf(
                     (wsum[0] + wsum[1]) + (wsum[2] + wsum[3])));
}

extern "C" void kernel_launch(void* const* d_in, const int* in_sizes, int n_in,
                              void* d_out, int out_size, void* d_ws, size_t ws_size,
                              hipStream_t stream) {
    const float* emissions   = (const float*)d_in[0];
    const float* transitions = (const float*)d_in[1];
    const float* start_t     = (const float*)d_in[2];
    const float* end_t       = (const float*)d_in[3];
    const int*   lengths     = (const int*)d_in[4];
    float* out = (float*)d_out;

    crf_forward<<<dim3(64), dim3(256), 0, stream>>>(
        emissions, transitions, start_t, end_t, lengths, out);
}